// Round 18
// baseline (127.779 us; speedup 1.0000x reference)
//
#include <hip/hip_runtime.h>
#include <math.h>

#define BATCH 2
#define NTOK 4096        // H*W
#define CDIM 256
#define NH 8
#define HD 32
#define MROWS (BATCH * NTOK)   // 8192

typedef __attribute__((ext_vector_type(8))) short bf16x8;
typedef __attribute__((ext_vector_type(4))) float f32x4;
typedef __attribute__((ext_vector_type(4))) unsigned u32x4;
typedef unsigned short ushort_t;

union frag_u { uint4 q; u32x4 u; bf16x8 b; };

__device__ __forceinline__ unsigned short f2bf(float f) {
    union { float f; unsigned u; } x; x.f = f;
    unsigned r = x.u + 0x7FFFu + ((x.u >> 16) & 1u);   // RNE
    return (unsigned short)(r >> 16);
}
__device__ __forceinline__ float bf2f(unsigned short h) {
    union { unsigned u; float f; } x; x.u = ((unsigned)h) << 16; return x.f;
}
__device__ __forceinline__ float exp2_fast(float x) {
    float r;
    asm("v_exp_f32 %0, %1\n\ts_nop 0" : "=v"(r) : "v"(x));   // proven r2-r16
    return r;
}
__device__ __forceinline__ unsigned cvt_pk_bf16(float a, float b) {
    unsigned r;   // lo16 = bf16(a), hi16 = bf16(b), RNE
    asm("v_cvt_pk_bf16_f32 %0, %1, %2" : "=v"(r) : "v"(a), "v"(b));
    return r;
}
__device__ __forceinline__ float max3f(float a, float b, float c) {
    float r;
    asm("v_max3_f32 %0, %1, %2, %3" : "=v"(r) : "v"(a), "v"(b), "v"(c));
    return r;
}
// f16 pair with RNE, packed into one dword
__device__ __forceinline__ unsigned pk_f16_rne(float a, float b) {
    union { _Float16 h[2]; unsigned u; } r;
    r.h[0] = (_Float16)a; r.h[1] = (_Float16)b;
    return r.u;
}
// C-frag dword pair (tile 2ks, tile 2ks+1) -> B-frag dword pair (w0, w1); proven r3-r16
__device__ __forceinline__ void permlane_pv(unsigned &a, unsigned &b) {
    asm("s_nop 1\n\t"
        "v_permlane32_swap_b32 %0, %1\n\t"
        "s_nop 1\n\t"
        "v_permlane16_swap_b32 %0, %1" : "+v"(a), "+v"(b));
}

// ---------------- prep: transpose + split W[K][N] -> Wt hi/lo [N][K] ----------------
__global__ __launch_bounds__(256) void prep_wt(
    const float* __restrict__ W, ushort_t* __restrict__ Whi, ushort_t* __restrict__ Wlo,
    int K, int N)
{
    __shared__ float T[32][33];
    const int tid = threadIdx.x;
    const int n0 = blockIdx.x * 32, k0 = blockIdx.y * 32;
    const int r = tid >> 3, c4 = (tid & 7) << 2;
    float4 v = *(const float4*)&W[(size_t)(k0 + r) * N + n0 + c4];
    T[r][c4 + 0] = v.x; T[r][c4 + 1] = v.y; T[r][c4 + 2] = v.z; T[r][c4 + 3] = v.w;
    __syncthreads();
    float f0 = T[c4 + 0][r], f1 = T[c4 + 1][r], f2 = T[c4 + 2][r], f3 = T[c4 + 3][r];
    unsigned h01 = cvt_pk_bf16(f0, f1), h23 = cvt_pk_bf16(f2, f3);
    union { unsigned u; float f; } a, b;
    a.u = h01 << 16; b.u = h01 & 0xFFFF0000u;
    unsigned l01 = cvt_pk_bf16(f0 - a.f, f1 - b.f);
    a.u = h23 << 16; b.u = h23 & 0xFFFF0000u;
    unsigned l23 = cvt_pk_bf16(f2 - a.f, f3 - b.f);
    size_t o = (size_t)(n0 + r) * K + k0 + c4;
    *(uint2*)&Whi[o] = make_uint2(h01, h23);
    *(uint2*)&Wlo[o] = make_uint2(l01, l23);
}

// ---------------- QKV projection: split-bf16 MFMA GEMM, fused X split ----------------
// r10/r16-proven. K now stored hi-only (2-term QK in attention drops the k-lo
// correction; q-lo is kept so Q rounding stays compensated).
__global__ __launch_bounds__(256) void qkv_mfma(
    const float* __restrict__ X,
    const ushort_t* __restrict__ Wthi, const ushort_t* __restrict__ Wtlo,  // [768][256]
    const float* __restrict__ bias,
    ushort_t* __restrict__ Qhi, ushort_t* __restrict__ Qlo,
    ushort_t* __restrict__ Khi, ushort_t* __restrict__ Vhi)
{
    __shared__ __align__(16) ushort_t Ah[64][40], Al[64][40], Bh[64][40], Bl[64][40];

    const int tid = threadIdx.x;
    const int w = tid >> 6, lane = tid & 63, lq = lane & 15, g = lane >> 4;
    const int wm = w >> 1, wn = w & 1;
    const int row0 = blockIdx.x * 64, col0 = blockIdx.y * 64;
    const int sr = tid >> 2, sc = (tid & 3) << 3;

    f32x4 acc[2][2] = {};

    for (int k0 = 0; k0 < CDIM; k0 += 32) {
        __syncthreads();
        {
            float4 xa = *(const float4*)&X[(size_t)(row0 + sr) * CDIM + k0 + sc];
            float4 xb = *(const float4*)&X[(size_t)(row0 + sr) * CDIM + k0 + sc + 4];
            unsigned h01 = cvt_pk_bf16(xa.x, xa.y), h23 = cvt_pk_bf16(xa.z, xa.w);
            unsigned h45 = cvt_pk_bf16(xb.x, xb.y), h67 = cvt_pk_bf16(xb.z, xb.w);
            union { unsigned u; float f; } t0, t1;
            t0.u = h01 << 16; t1.u = h01 & 0xFFFF0000u;
            unsigned l01 = cvt_pk_bf16(xa.x - t0.f, xa.y - t1.f);
            t0.u = h23 << 16; t1.u = h23 & 0xFFFF0000u;
            unsigned l23 = cvt_pk_bf16(xa.z - t0.f, xa.w - t1.f);
            t0.u = h45 << 16; t1.u = h45 & 0xFFFF0000u;
            unsigned l45 = cvt_pk_bf16(xb.x - t0.f, xb.y - t1.f);
            t0.u = h67 << 16; t1.u = h67 & 0xFFFF0000u;
            unsigned l67 = cvt_pk_bf16(xb.z - t0.f, xb.w - t1.f);
            *(uint4*)&Ah[sr][sc] = make_uint4(h01, h23, h45, h67);
            *(uint4*)&Al[sr][sc] = make_uint4(l01, l23, l45, l67);
            *(uint4*)&Bh[sr][sc] = *(const uint4*)&Wthi[(size_t)(col0 + sr) * CDIM + k0 + sc];
            *(uint4*)&Bl[sr][sc] = *(const uint4*)&Wtlo[(size_t)(col0 + sr) * CDIM + k0 + sc];
        }
        __syncthreads();

        bf16x8 ah[2], al[2], bh[2], bl[2];
        #pragma unroll
        for (int i = 0; i < 2; ++i) {
            ah[i] = *(const bf16x8*)&Ah[wm * 32 + i * 16 + lq][g * 8];
            al[i] = *(const bf16x8*)&Al[wm * 32 + i * 16 + lq][g * 8];
        }
        #pragma unroll
        for (int j = 0; j < 2; ++j) {
            bh[j] = *(const bf16x8*)&Bh[wn * 32 + j * 16 + lq][g * 8];
            bl[j] = *(const bf16x8*)&Bl[wn * 32 + j * 16 + lq][g * 8];
        }
        #pragma unroll
        for (int i = 0; i < 2; ++i)
            #pragma unroll
            for (int j = 0; j < 2; ++j) {
                acc[i][j] = __builtin_amdgcn_mfma_f32_16x16x32_bf16(ah[i], bh[j], acc[i][j], 0, 0, 0);
                acc[i][j] = __builtin_amdgcn_mfma_f32_16x16x32_bf16(ah[i], bl[j], acc[i][j], 0, 0, 0);
                acc[i][j] = __builtin_amdgcn_mfma_f32_16x16x32_bf16(al[i], bh[j], acc[i][j], 0, 0, 0);
            }
    }

    const int s = col0 >> 8;            // 0=Q 1=K 2=V (block-uniform)
    const int b_ = row0 >> 12;
    const int nb0 = (row0 & (NTOK - 1)) + wm * 32 + 4 * g;
    const float QSC = (float)(1.4426950408889634 / 5.656854249492381);

    #pragma unroll
    for (int j = 0; j < 2; ++j) {
        const int gcol = col0 + wn * 32 + j * 16 + lq;
        const float bv = bias[gcol];
        const int h = (gcol >> 5) & 7, e = gcol & 31;
        const int bh_ = b_ * NH + h;
        #pragma unroll
        for (int i = 0; i < 2; ++i) {
            #pragma unroll
            for (int r = 0; r < 4; ++r) {
                const int n = nb0 + i * 16 + r;
                float val = acc[i][j][r] + bv;
                if (s == 0) {
                    val *= QSC;
                    unsigned short hh = f2bf(val);
                    unsigned short ll = f2bf(val - bf2f(hh));
                    size_t idx = ((size_t)bh_ * NTOK + n) * HD + e;
                    Qhi[idx] = hh; Qlo[idx] = ll;
                } else if (s == 1) {
                    Khi[((size_t)bh_ * NTOK + n) * HD + e] = f2bf(val);
                } else {
                    Vhi[((size_t)bh_ * HD + e) * NTOK + n] = f2bf(val);
                }
            }
        }
    }
}

// ---------------- MFMA flash attention v17: 2-term QK (K hi-only) + setprio ----------------
// v16 structure (kv-split 2048 blocks, defer-max, l-via-ones-MFMA, normalized
// f16 partials + l,m f32; max-reconciled merge). Changes:
// (1) K single-bf16: QK = kh*qh + kh*ql (drops qh*kl; k-rounding error
//     ~1.6e-3 in log2 domain, cancels in softmax normalization). Halves K LDS
//     traffic+staging, QK MFMAs 12->8, removes the Klo buffer entirely.
// (2) s_setprio(1) around MFMA clusters (T5): 8 independent blocks/CU give the
//     wave phase-diversity where setprio pays (m191 regime, not m190's lockstep).
__global__ __launch_bounds__(256, 3) void attn_v17(
    const ushort_t* __restrict__ Qhi, const ushort_t* __restrict__ Qlo,
    const ushort_t* __restrict__ Khi, const ushort_t* __restrict__ Vhi,
    ushort_t* __restrict__ P_O, float* __restrict__ P_l, float* __restrict__ P_m)
{
    __shared__ __align__(16) ushort_t KH[64][44];   // pitch 88B (proven)
    __shared__ __align__(16) ushort_t VH[32][68];   // pitch 136B (proven)

    const int tid = threadIdx.x;
    const int w = tid >> 6, lane = tid & 63, lq = lane & 15, g = lane >> 4;
    const int bx = blockIdx.x;
    const int bh = bx & 15, qc = (bx >> 4) & 63, hf = bx >> 10;
    const int q0 = qc * 64 + w * 16;
    const int kb = bh * (NTOK * HD);
    const int vb = bh * (HD * NTOK);

    // Q fragment (pre-scaled by scale*log2e in qkv epilogue)
    bf16x8 qh, ql;
    {
        const int qi = kb + (q0 + lq) * HD + g * 8;
        qh = *(const bf16x8*)(Qhi + qi);
        ql = *(const bf16x8*)(Qlo + qi);
    }

    // ones A-fragment for the l-MFMA
    const bf16x8 vones = {0x3F80, 0x3F80, 0x3F80, 0x3F80, 0x3F80, 0x3F80, 0x3F80, 0x3F80};

    // staging slots (256 threads); pointers walk one tile per step
    const int kr = tid >> 2, kc = (tid & 3) << 3;
    const int vr = tid >> 3, vc = (tid & 7) << 3;
    const ushort_t* pKH = Khi + kb + (hf * 2048 + kr) * HD + kc;
    const ushort_t* pVH = Vhi + vb + vr * NTOK + hf * 2048 + vc;

    uint4 sKH = *(const uint4*)pKH;  pKH += 64 * HD;
    uint4 sVH = *(const uint4*)pVH;  pVH += 64;

    f32x4 o0 = {}, o1 = {};
    f32x4 lfrag = {};
    float m_ = -1e30f;

    for (int step = 0; step < 32; ++step) {
        __syncthreads();
        *(uint4*)&KH[kr][kc] = sKH;
        *(uint4*)&VH[vr][vc] = sVH;
        __syncthreads();

        // issue next-step loads (final-step overrun: in-workspace, unused)
        sKH = *(const uint4*)pKH;  pKH += 64 * HD;
        sVH = *(const uint4*)pVH;  pVH += 64;

        bf16x8 kh[4];
        #pragma unroll
        for (int t = 0; t < 4; ++t)
            kh[t] = *(const bf16x8*)&KH[16 * t + lq][g * 8];

        f32x4 sc[4];
        __builtin_amdgcn_s_setprio(1);
        #pragma unroll
        for (int t = 0; t < 4; ++t) {
            f32x4 cc = {0.f, 0.f, 0.f, 0.f};
            cc = __builtin_amdgcn_mfma_f32_16x16x32_bf16(kh[t], qh, cc, 0, 0, 0);
            cc = __builtin_amdgcn_mfma_f32_16x16x32_bf16(kh[t], ql, cc, 0, 0, 0);
            sc[t] = cc;
        }
        __builtin_amdgcn_s_setprio(0);

        // row max via max3 tree
        float a0 = max3f(sc[0][0], sc[0][1], sc[0][2]);
        float a1 = max3f(sc[0][3], sc[1][0], sc[1][1]);
        float a2 = max3f(sc[1][2], sc[1][3], sc[2][0]);
        float a3 = max3f(sc[2][1], sc[2][2], sc[2][3]);
        float a4 = max3f(sc[3][0], sc[3][1], sc[3][2]);
        float b0 = max3f(a0, a1, a2);
        float b1 = max3f(a3, a4, sc[3][3]);
        float mx = fmaxf(b0, b1);
        mx = fmaxf(mx, __shfl_xor(mx, 16));
        mx = fmaxf(mx, __shfl_xor(mx, 32));

        // defer-max: rescale only when the bound would be violated (rare)
        if (!__all(mx <= m_ + 8.0f)) {
            float mnew = fmaxf(m_, mx);
            float rs = exp2_fast(m_ - mnew);
            m_ = mnew;
            lfrag *= rs;
            o0 *= rs;
            o1 *= rs;
        }

        unsigned ph[4][2];
        #pragma unroll
        for (int t = 0; t < 4; ++t) {
            float p0 = exp2_fast(sc[t][0] - m_);
            float p1 = exp2_fast(sc[t][1] - m_);
            float p2 = exp2_fast(sc[t][2] - m_);
            float p3 = exp2_fast(sc[t][3] - m_);
            ph[t][0] = cvt_pk_bf16(p0, p1);
            ph[t][1] = cvt_pk_bf16(p2, p3);
        }

        #pragma unroll
        for (int ks = 0; ks < 2; ++ks) {
            unsigned h00 = ph[2 * ks][0], h10 = ph[2 * ks + 1][0];
            unsigned h01 = ph[2 * ks][1], h11 = ph[2 * ks + 1][1];
            permlane_pv(h00, h10);
            permlane_pv(h01, h11);
            frag_u PH; PH.u = (u32x4){h00, h01, h10, h11};
            bf16x8 v0f = *(const bf16x8*)&VH[lq][ks * 32 + g * 8];
            bf16x8 v1f = *(const bf16x8*)&VH[16 + lq][ks * 32 + g * 8];
            __builtin_amdgcn_s_setprio(1);
            o0 = __builtin_amdgcn_mfma_f32_16x16x32_bf16(v0f, PH.b, o0, 0, 0, 0);
            o1 = __builtin_amdgcn_mfma_f32_16x16x32_bf16(v1f, PH.b, o1, 0, 0, 0);
            lfrag = __builtin_amdgcn_mfma_f32_16x16x32_bf16(vones, PH.b, lfrag, 0, 0, 0);
            __builtin_amdgcn_s_setprio(0);
        }
    }

    // l complete per q-column in every lfrag register (rows identical)
    const float ls = lfrag[0];

    // normalize partial (|o/l| <= max|V| -- f16-safe), store f16 RNE + l,m f32
    const float invl = 1.0f / ls;
    const int qg = q0 + lq;
    const size_t prow = ((size_t)(hf * 16 + bh) * NTOK + qg);
    {
        unsigned w0 = pk_f16_rne(o0[0] * invl, o0[1] * invl);
        unsigned w1 = pk_f16_rne(o0[2] * invl, o0[3] * invl);
        *(uint2*)&P_O[prow * 32 + 4 * g] = make_uint2(w0, w1);
        unsigned w2 = pk_f16_rne(o1[0] * invl, o1[1] * invl);
        unsigned w3 = pk_f16_rne(o1[2] * invl, o1[3] * invl);
        *(uint2*)&P_O[prow * 32 + 16 + 4 * g] = make_uint2(w2, w3);
    }
    if (g == 0) {
        P_l[prow] = ls;
        P_m[prow] = m_;
    }
}

// ---------------- merge: reconcile maxima, weighted average -> AO bf16 hi/lo ----------------
__global__ __launch_bounds__(256) void merge_norm(
    const ushort_t* __restrict__ P_O, const float* __restrict__ P_l,
    const float* __restrict__ P_m,
    ushort_t* __restrict__ AOhi, ushort_t* __restrict__ AOlo)
{
    const int t = blockIdx.x * 256 + threadIdx.x;     // 262144 threads
    const int bhq = t >> 2;                           // bh*4096 + q
    const int dq = (t & 3) << 3;
    union { uint4 q; _Float16 h[8]; } a, b;
    a.q = *(const uint4*)&P_O[(size_t)bhq * 32 + dq];
    b.q = *(const uint4*)&P_O[(size_t)(65536 + bhq) * 32 + dq];
    const float l0 = P_l[bhq], l1 = P_l[65536 + bhq];
    const float m0 = P_m[bhq], m1 = P_m[65536 + bhq];
    const float mstar = fmaxf(m0, m1);
    const float w0r = exp2_fast(m0 - mstar) * l0;
    const float w1r = exp2_fast(m1 - mstar) * l1;
    const float inv = 1.0f / (w0r + w1r);
    const float w0 = w0r * inv, w1 = w1r * inv;
    const int bh = bhq >> 12, q = bhq & 4095;
    const size_t ob = ((size_t)(bh >> 3) * NTOK + q) * CDIM + (bh & 7) * 32 + dq;

    float f[8];
    #pragma unroll
    for (int i = 0; i < 8; ++i) f[i] = (float)a.h[i] * w0 + (float)b.h[i] * w1;

    unsigned h01 = cvt_pk_bf16(f[0], f[1]), h23 = cvt_pk_bf16(f[2], f[3]);
    unsigned h45 = cvt_pk_bf16(f[4], f[5]), h67 = cvt_pk_bf16(f[6], f[7]);
    union { unsigned u; float ff; } x, y;
    x.u = h01 << 16; y.u = h01 & 0xFFFF0000u;
    unsigned l01 = cvt_pk_bf16(f[0] - x.ff, f[1] - y.ff);
    x.u = h23 << 16; y.u = h23 & 0xFFFF0000u;
    unsigned l23 = cvt_pk_bf16(f[2] - x.ff, f[3] - y.ff);
    x.u = h45 << 16; y.u = h45 & 0xFFFF0000u;
    unsigned l45 = cvt_pk_bf16(f[4] - x.ff, f[5] - y.ff);
    x.u = h67 << 16; y.u = h67 & 0xFFFF0000u;
    unsigned l67 = cvt_pk_bf16(f[6] - x.ff, f[7] - y.ff);

    *(uint4*)&AOhi[ob] = make_uint4(h01, h23, h45, h67);
    *(uint4*)&AOlo[ob] = make_uint4(l01, l23, l45, l67);
}

// ---------------- Output projection: split-bf16 MFMA GEMM (proven r10) ----------------
__global__ __launch_bounds__(256) void proj_mfma(
    const ushort_t* __restrict__ AOhi, const ushort_t* __restrict__ AOlo,
    const ushort_t* __restrict__ Wthi, const ushort_t* __restrict__ Wtlo,  // [256][256]
    const float* __restrict__ bias, float* __restrict__ out)
{
    __shared__ __align__(16) ushort_t Ah[64][40], Al[64][40], Bh[64][40], Bl[64][40];

    const int tid = threadIdx.x;
    const int w = tid >> 6, lane = tid & 63, lq = lane & 15, g = lane >> 4;
    const int wm = w >> 1, wn = w & 1;
    const int row0 = blockIdx.x * 64, col0 = blockIdx.y * 64;
    const int sr = tid >> 2, sc = (tid & 3) << 3;

    f32x4 acc[2][2] = {};

    for (int k0 = 0; k0 < CDIM; k0 += 32) {
        __syncthreads();
        *(uint4*)&Ah[sr][sc] = *(const uint4*)&AOhi[(size_t)(row0 + sr) * CDIM + k0 + sc];
        *(uint4*)&Al[sr][sc] = *(const uint4*)&AOlo[(size_t)(row0 + sr) * CDIM + k0 + sc];
        *(uint4*)&Bh[sr][sc] = *(const uint4*)&Wthi[(size_t)(col0 + sr) * CDIM + k0 + sc];
        *(uint4*)&Bl[sr][sc] = *(const uint4*)&Wtlo[(size_t)(col0 + sr) * CDIM + k0 + sc];
        __syncthreads();

        bf16x8 ah[2], al[2], bh[2], bl[2];
        #pragma unroll
        for (int i = 0; i < 2; ++i) {
            ah[i] = *(const bf16x8*)&Ah[wm * 32 + i * 16 + lq][g * 8];
            al[i] = *(const bf16x8*)&Al[wm * 32 + i * 16 + lq][g * 8];
        }
        #pragma unroll
        for (int j = 0; j < 2; ++j) {
            bh[j] = *(const bf16x8*)&Bh[wn * 32 + j * 16 + lq][g * 8];
            bl[j] = *(const bf16x8*)&Bl[wn * 32 + j * 16 + lq][g * 8];
        }
        #pragma unroll
        for (int i = 0; i < 2; ++i)
            #pragma unroll
            for (int j = 0; j < 2; ++j) {
                acc[i][j] = __builtin_amdgcn_mfma_f32_16x16x32_bf16(ah[i], bh[j], acc[i][j], 0, 0, 0);
                acc[i][j] = __builtin_amdgcn_mfma_f32_16x16x32_bf16(ah[i], bl[j], acc[i][j], 0, 0, 0);
                acc[i][j] = __builtin_amdgcn_mfma_f32_16x16x32_bf16(al[i], bh[j], acc[i][j], 0, 0, 0);
            }
    }

    #pragma unroll
    for (int j = 0; j < 2; ++j) {
        const int gcol = col0 + wn * 32 + j * 16 + lq;
        const float bv = bias[gcol];
        #pragma unroll
        for (int i = 0; i < 2; ++i) {
            #pragma unroll
            for (int r = 0; r < 4; ++r) {
                const int grow = row0 + wm * 32 + i * 16 + 4 * g + r;
                out[(size_t)grow * CDIM + gcol] = acc[i][j][r] + bv;
            }
        }
    }
}

extern "C" void kernel_launch(void* const* d_in, const int* in_sizes, int n_in,
                              void* d_out, int out_size, void* d_ws, size_t ws_size,
                              hipStream_t stream)
{
    const float* x      = (const float*)d_in[0];
    const float* w_qkv  = (const float*)d_in[1];
    const float* b_qkv  = (const float*)d_in[2];
    const float* w_proj = (const float*)d_in[3];
    const float* b_proj = (const float*)d_in[4];
    // d_in[5] rel_bias: per-head scalar over the full score matrix -> softmax no-op.

    float* out = (float*)d_out;

    // ws layout (26MB, phase-safe):
    //  [ 0, 8M): Q hi/lo           (live: qkv->attn)
    //  [ 8,12M): K hi               (qkv->attn), then AOhi (merge->proj)
    //  [12,16M): V hi               (qkv->attn), then AOlo (merge->proj)
    //  [16,17M): weights Wqt/Wpt hi/lo
    //  [17,25M): partials P_O (attn->merge)
    //  [25M+):   P_l (512KB), P_m (512KB)
    char* p = (char*)d_ws;
    ushort_t* Qhi   = (ushort_t*)(p);
    ushort_t* Qlo   = (ushort_t*)(p + 4194304);
    ushort_t* Khi   = (ushort_t*)(p + 8388608);
    ushort_t* Vhi   = (ushort_t*)(p + 12582912);
    ushort_t* Wqthi = (ushort_t*)(p + 16777216);
    ushort_t* Wqtlo = (ushort_t*)(p + 16777216 + 393216);
    ushort_t* Wpthi = (ushort_t*)(p + 16777216 + 786432);
    ushort_t* Wptlo = (ushort_t*)(p + 16777216 + 917504);
    ushort_t* P_O   = (ushort_t*)(p + 17825792);            // 17M, 8MB
    float*    P_l   = (float*)(p + 26214400);               // 512KB
    float*    P_m   = (float*)(p + 26738688);               // 512KB
    ushort_t* AOhi  = Khi;                                  // K dead after attn
    ushort_t* AOlo  = Vhi;                                  // V dead after attn

    // 0) prep: transpose+split weights (X split fused into qkv_mfma)
    prep_wt<<<dim3(24, 8), 256, 0, stream>>>(w_qkv, Wqthi, Wqtlo, 256, 768);
    prep_wt<<<dim3(8, 8), 256, 0, stream>>>(w_proj, Wpthi, Wptlo, 256, 256);

    // 1) QKV projection (MFMA, fused f32->hi/lo staging; K/V hi-only)
    qkv_mfma<<<dim3(MROWS / 64, 768 / 64), 256, 0, stream>>>(
        x, Wqthi, Wqtlo, b_qkv, Qhi, Qlo, Khi, Vhi);

    // 2) attention halves (2048 blocks, 2-term QK, setprio)
    attn_v17<<<2048, 256, 0, stream>>>(Qhi, Qlo, Khi, Vhi, P_O, P_l, P_m);

    // 3) merge partials (max-reconciled weighted average) -> AO bf16 hi/lo
    merge_norm<<<1024, 256, 0, stream>>>(P_O, P_l, P_m, AOhi, AOlo);

    // 4) output projection (MFMA)
    proj_mfma<<<dim3(MROWS / 64, CDIM / 64), 256, 0, stream>>>(
        AOhi, AOlo, Wpthi, Wptlo, b_proj, out);
}

// Round 19
// 121.289 us; speedup vs baseline: 1.0535x; 1.0535x over previous
//
#include <hip/hip_runtime.h>
#include <math.h>

#define BATCH 2
#define NTOK 4096        // H*W
#define CDIM 256
#define NH 8
#define HD 32
#define MROWS (BATCH * NTOK)   // 8192

typedef __attribute__((ext_vector_type(8))) short bf16x8;
typedef __attribute__((ext_vector_type(4))) float f32x4;
typedef __attribute__((ext_vector_type(4))) unsigned u32x4;
typedef unsigned short ushort_t;

union frag_u { uint4 q; u32x4 u; bf16x8 b; };

__device__ __forceinline__ unsigned short f2bf(float f) {
    union { float f; unsigned u; } x; x.f = f;
    unsigned r = x.u + 0x7FFFu + ((x.u >> 16) & 1u);   // RNE
    return (unsigned short)(r >> 16);
}
__device__ __forceinline__ float bf2f(unsigned short h) {
    union { unsigned u; float f; } x; x.u = ((unsigned)h) << 16; return x.f;
}
__device__ __forceinline__ float exp2_fast(float x) {
    float r;
    asm("v_exp_f32 %0, %1\n\ts_nop 0" : "=v"(r) : "v"(x));   // proven r2-r18
    return r;
}
__device__ __forceinline__ unsigned cvt_pk_bf16(float a, float b) {
    unsigned r;   // lo16 = bf16(a), hi16 = bf16(b), RNE
    asm("v_cvt_pk_bf16_f32 %0, %1, %2" : "=v"(r) : "v"(a), "v"(b));
    return r;
}
__device__ __forceinline__ float max3f(float a, float b, float c) {
    float r;
    asm("v_max3_f32 %0, %1, %2, %3" : "=v"(r) : "v"(a), "v"(b), "v"(c));
    return r;
}
// f16 pair with RNE, packed into one dword
__device__ __forceinline__ unsigned pk_f16_rne(float a, float b) {
    union { _Float16 h[2]; unsigned u; } r;
    r.h[0] = (_Float16)a; r.h[1] = (_Float16)b;
    return r.u;
}
// C-frag dword pair (tile 2ks, tile 2ks+1) -> B-frag dword pair (w0, w1); proven r3-r18
__device__ __forceinline__ void permlane_pv(unsigned &a, unsigned &b) {
    asm("s_nop 1\n\t"
        "v_permlane32_swap_b32 %0, %1\n\t"
        "s_nop 1\n\t"
        "v_permlane16_swap_b32 %0, %1" : "+v"(a), "+v"(b));
}

// ---------------- prep: transpose + split W[K][N] -> Wt hi/lo [N][K] ----------------
__global__ __launch_bounds__(256) void prep_wt(
    const float* __restrict__ W, ushort_t* __restrict__ Whi, ushort_t* __restrict__ Wlo,
    int K, int N)
{
    __shared__ float T[32][33];
    const int tid = threadIdx.x;
    const int n0 = blockIdx.x * 32, k0 = blockIdx.y * 32;
    const int r = tid >> 3, c4 = (tid & 7) << 2;
    float4 v = *(const float4*)&W[(size_t)(k0 + r) * N + n0 + c4];
    T[r][c4 + 0] = v.x; T[r][c4 + 1] = v.y; T[r][c4 + 2] = v.z; T[r][c4 + 3] = v.w;
    __syncthreads();
    float f0 = T[c4 + 0][r], f1 = T[c4 + 1][r], f2 = T[c4 + 2][r], f3 = T[c4 + 3][r];
    unsigned h01 = cvt_pk_bf16(f0, f1), h23 = cvt_pk_bf16(f2, f3);
    union { unsigned u; float f; } a, b;
    a.u = h01 << 16; b.u = h01 & 0xFFFF0000u;
    unsigned l01 = cvt_pk_bf16(f0 - a.f, f1 - b.f);
    a.u = h23 << 16; b.u = h23 & 0xFFFF0000u;
    unsigned l23 = cvt_pk_bf16(f2 - a.f, f3 - b.f);
    size_t o = (size_t)(n0 + r) * K + k0 + c4;
    *(uint2*)&Whi[o] = make_uint2(h01, h23);
    *(uint2*)&Wlo[o] = make_uint2(l01, l23);
}

// ---------------- QKV projection: split-bf16 MFMA GEMM, fused X split ----------------
// r10/r16-proven. Q/K/V all stored hi-only now (attention uses pure-bf16 QK^T;
// measured error floor is V's bf16 storage rounding, with 3.9x threshold headroom).
__global__ __launch_bounds__(256) void qkv_mfma(
    const float* __restrict__ X,
    const ushort_t* __restrict__ Wthi, const ushort_t* __restrict__ Wtlo,  // [768][256]
    const float* __restrict__ bias,
    ushort_t* __restrict__ Qhi, ushort_t* __restrict__ Khi, ushort_t* __restrict__ Vhi)
{
    __shared__ __align__(16) ushort_t Ah[64][40], Al[64][40], Bh[64][40], Bl[64][40];

    const int tid = threadIdx.x;
    const int w = tid >> 6, lane = tid & 63, lq = lane & 15, g = lane >> 4;
    const int wm = w >> 1, wn = w & 1;
    const int row0 = blockIdx.x * 64, col0 = blockIdx.y * 64;
    const int sr = tid >> 2, sc = (tid & 3) << 3;

    f32x4 acc[2][2] = {};

    for (int k0 = 0; k0 < CDIM; k0 += 32) {
        __syncthreads();
        {
            float4 xa = *(const float4*)&X[(size_t)(row0 + sr) * CDIM + k0 + sc];
            float4 xb = *(const float4*)&X[(size_t)(row0 + sr) * CDIM + k0 + sc + 4];
            unsigned h01 = cvt_pk_bf16(xa.x, xa.y), h23 = cvt_pk_bf16(xa.z, xa.w);
            unsigned h45 = cvt_pk_bf16(xb.x, xb.y), h67 = cvt_pk_bf16(xb.z, xb.w);
            union { unsigned u; float f; } t0, t1;
            t0.u = h01 << 16; t1.u = h01 & 0xFFFF0000u;
            unsigned l01 = cvt_pk_bf16(xa.x - t0.f, xa.y - t1.f);
            t0.u = h23 << 16; t1.u = h23 & 0xFFFF0000u;
            unsigned l23 = cvt_pk_bf16(xa.z - t0.f, xa.w - t1.f);
            t0.u = h45 << 16; t1.u = h45 & 0xFFFF0000u;
            unsigned l45 = cvt_pk_bf16(xb.x - t0.f, xb.y - t1.f);
            t0.u = h67 << 16; t1.u = h67 & 0xFFFF0000u;
            unsigned l67 = cvt_pk_bf16(xb.z - t0.f, xb.w - t1.f);
            *(uint4*)&Ah[sr][sc] = make_uint4(h01, h23, h45, h67);
            *(uint4*)&Al[sr][sc] = make_uint4(l01, l23, l45, l67);
            *(uint4*)&Bh[sr][sc] = *(const uint4*)&Wthi[(size_t)(col0 + sr) * CDIM + k0 + sc];
            *(uint4*)&Bl[sr][sc] = *(const uint4*)&Wtlo[(size_t)(col0 + sr) * CDIM + k0 + sc];
        }
        __syncthreads();

        bf16x8 ah[2], al[2], bh[2], bl[2];
        #pragma unroll
        for (int i = 0; i < 2; ++i) {
            ah[i] = *(const bf16x8*)&Ah[wm * 32 + i * 16 + lq][g * 8];
            al[i] = *(const bf16x8*)&Al[wm * 32 + i * 16 + lq][g * 8];
        }
        #pragma unroll
        for (int j = 0; j < 2; ++j) {
            bh[j] = *(const bf16x8*)&Bh[wn * 32 + j * 16 + lq][g * 8];
            bl[j] = *(const bf16x8*)&Bl[wn * 32 + j * 16 + lq][g * 8];
        }
        #pragma unroll
        for (int i = 0; i < 2; ++i)
            #pragma unroll
            for (int j = 0; j < 2; ++j) {
                acc[i][j] = __builtin_amdgcn_mfma_f32_16x16x32_bf16(ah[i], bh[j], acc[i][j], 0, 0, 0);
                acc[i][j] = __builtin_amdgcn_mfma_f32_16x16x32_bf16(ah[i], bl[j], acc[i][j], 0, 0, 0);
                acc[i][j] = __builtin_amdgcn_mfma_f32_16x16x32_bf16(al[i], bh[j], acc[i][j], 0, 0, 0);
            }
    }

    const int s = col0 >> 8;            // 0=Q 1=K 2=V (block-uniform)
    const int b_ = row0 >> 12;
    const int nb0 = (row0 & (NTOK - 1)) + wm * 32 + 4 * g;
    const float QSC = (float)(1.4426950408889634 / 5.656854249492381);

    #pragma unroll
    for (int j = 0; j < 2; ++j) {
        const int gcol = col0 + wn * 32 + j * 16 + lq;
        const float bv = bias[gcol];
        const int h = (gcol >> 5) & 7, e = gcol & 31;
        const int bh_ = b_ * NH + h;
        #pragma unroll
        for (int i = 0; i < 2; ++i) {
            #pragma unroll
            for (int r = 0; r < 4; ++r) {
                const int n = nb0 + i * 16 + r;
                float val = acc[i][j][r] + bv;
                if (s == 0) {
                    Qhi[((size_t)bh_ * NTOK + n) * HD + e] = f2bf(val * QSC);
                } else if (s == 1) {
                    Khi[((size_t)bh_ * NTOK + n) * HD + e] = f2bf(val);
                } else {
                    Vhi[((size_t)bh_ * HD + e) * NTOK + n] = f2bf(val);
                }
            }
        }
    }
}

// ---------------- MFMA flash attention v19: KVBLK=128 (2x64 passes), 1-term QK ----------------
// v17 structure (kv-split 2048 blocks, defer-max, l-via-ones-MFMA, normalized
// f16 partials + l,m f32; max-reconciled merge; setprio). Changes:
// (1) KVBLK=128: one LDS stage (K[128][44] + V[32][132], 19.7KB) computed as
//     two sequential 64-kv passes -> barriers per block 64 -> 32; prefetch now
//     covered by a full 128-kv compute phase. 8 blocks/CU still fit (158KB).
// (2) pure-bf16 QK^T (Q hi-only): symmetric to r18's measured-free K-lo drop;
//     error floor stays dominated by V's bf16 storage (2^-9), 3.9x headroom.
__global__ __launch_bounds__(256, 3) void attn_v19(
    const ushort_t* __restrict__ Qhi,
    const ushort_t* __restrict__ Khi, const ushort_t* __restrict__ Vhi,
    ushort_t* __restrict__ P_O, float* __restrict__ P_l, float* __restrict__ P_m)
{
    __shared__ __align__(16) ushort_t KH[128][44];   // pitch 88B (proven banks)
    __shared__ __align__(16) ushort_t VH[32][132];   // pitch 264B (same bank residues as 136B)

    const int tid = threadIdx.x;
    const int w = tid >> 6, lane = tid & 63, lq = lane & 15, g = lane >> 4;
    const int bx = blockIdx.x;
    const int bh = bx & 15, qc = (bx >> 4) & 63, hf = bx >> 10;
    const int q0 = qc * 64 + w * 16;
    const int kb = bh * (NTOK * HD);
    const int vb = bh * (HD * NTOK);

    // Q fragment (pre-scaled by scale*log2e; hi-only)
    bf16x8 qh;
    {
        const int qi = kb + (q0 + lq) * HD + g * 8;
        qh = *(const bf16x8*)(Qhi + qi);
    }

    // ones A-fragment for the l-MFMA
    const bf16x8 vones = {0x3F80, 0x3F80, 0x3F80, 0x3F80, 0x3F80, 0x3F80, 0x3F80, 0x3F80};

    // staging: K tile 128x64B = 512 chunks, V tile 32x256B = 512 chunks; 2 each/thread
    const int kr0 = tid >> 2,          kc0 = (tid & 3) << 3;
    const int kr1 = (tid + 256) >> 2,  kc1 = ((tid + 256) & 3) << 3;
    const int vr0 = tid >> 4,          vc0 = (tid & 15) << 3;
    const int vr1 = (tid + 256) >> 4,  vc1 = ((tid + 256) & 15) << 3;
    const ushort_t* pK0 = Khi + kb + (hf * 2048 + kr0) * HD + kc0;
    const ushort_t* pK1 = Khi + kb + (hf * 2048 + kr1) * HD + kc1;
    const ushort_t* pV0 = Vhi + vb + vr0 * NTOK + hf * 2048 + vc0;
    const ushort_t* pV1 = Vhi + vb + vr1 * NTOK + hf * 2048 + vc1;

    uint4 sK0 = *(const uint4*)pK0;  pK0 += 128 * HD;
    uint4 sK1 = *(const uint4*)pK1;  pK1 += 128 * HD;
    uint4 sV0 = *(const uint4*)pV0;  pV0 += 128;
    uint4 sV1 = *(const uint4*)pV1;  pV1 += 128;

    f32x4 o0 = {}, o1 = {};
    f32x4 lfrag = {};
    float m_ = -1e30f;

    for (int stage = 0; stage < 16; ++stage) {
        __syncthreads();
        *(uint4*)&KH[kr0][kc0] = sK0;
        *(uint4*)&KH[kr1][kc1] = sK1;
        *(uint4*)&VH[vr0][vc0] = sV0;
        *(uint4*)&VH[vr1][vc1] = sV1;
        __syncthreads();

        // issue next-stage loads (final-stage overrun: in-workspace, unused)
        sK0 = *(const uint4*)pK0;  pK0 += 128 * HD;
        sK1 = *(const uint4*)pK1;  pK1 += 128 * HD;
        sV0 = *(const uint4*)pV0;  pV0 += 128;
        sV1 = *(const uint4*)pV1;  pV1 += 128;

        #pragma unroll
        for (int pass = 0; pass < 2; ++pass) {
            bf16x8 kh[4];
            #pragma unroll
            for (int t = 0; t < 4; ++t)
                kh[t] = *(const bf16x8*)&KH[pass * 64 + 16 * t + lq][g * 8];

            f32x4 sc[4];
            __builtin_amdgcn_s_setprio(1);
            #pragma unroll
            for (int t = 0; t < 4; ++t) {
                f32x4 cc = {0.f, 0.f, 0.f, 0.f};
                sc[t] = __builtin_amdgcn_mfma_f32_16x16x32_bf16(kh[t], qh, cc, 0, 0, 0);
            }
            __builtin_amdgcn_s_setprio(0);

            // row max via max3 tree
            float a0 = max3f(sc[0][0], sc[0][1], sc[0][2]);
            float a1 = max3f(sc[0][3], sc[1][0], sc[1][1]);
            float a2 = max3f(sc[1][2], sc[1][3], sc[2][0]);
            float a3 = max3f(sc[2][1], sc[2][2], sc[2][3]);
            float a4 = max3f(sc[3][0], sc[3][1], sc[3][2]);
            float b0 = max3f(a0, a1, a2);
            float b1 = max3f(a3, a4, sc[3][3]);
            float mx = fmaxf(b0, b1);
            mx = fmaxf(mx, __shfl_xor(mx, 16));
            mx = fmaxf(mx, __shfl_xor(mx, 32));

            // defer-max: rescale only when the bound would be violated (rare)
            if (!__all(mx <= m_ + 8.0f)) {
                float mnew = fmaxf(m_, mx);
                float rs = exp2_fast(m_ - mnew);
                m_ = mnew;
                lfrag *= rs;
                o0 *= rs;
                o1 *= rs;
            }

            unsigned ph[4][2];
            #pragma unroll
            for (int t = 0; t < 4; ++t) {
                float p0 = exp2_fast(sc[t][0] - m_);
                float p1 = exp2_fast(sc[t][1] - m_);
                float p2 = exp2_fast(sc[t][2] - m_);
                float p3 = exp2_fast(sc[t][3] - m_);
                ph[t][0] = cvt_pk_bf16(p0, p1);
                ph[t][1] = cvt_pk_bf16(p2, p3);
            }

            #pragma unroll
            for (int ks = 0; ks < 2; ++ks) {
                unsigned h00 = ph[2 * ks][0], h10 = ph[2 * ks + 1][0];
                unsigned h01 = ph[2 * ks][1], h11 = ph[2 * ks + 1][1];
                permlane_pv(h00, h10);
                permlane_pv(h01, h11);
                frag_u PH; PH.u = (u32x4){h00, h01, h10, h11};
                bf16x8 v0f = *(const bf16x8*)&VH[lq][pass * 64 + ks * 32 + g * 8];
                bf16x8 v1f = *(const bf16x8*)&VH[16 + lq][pass * 64 + ks * 32 + g * 8];
                __builtin_amdgcn_s_setprio(1);
                o0 = __builtin_amdgcn_mfma_f32_16x16x32_bf16(v0f, PH.b, o0, 0, 0, 0);
                o1 = __builtin_amdgcn_mfma_f32_16x16x32_bf16(v1f, PH.b, o1, 0, 0, 0);
                lfrag = __builtin_amdgcn_mfma_f32_16x16x32_bf16(vones, PH.b, lfrag, 0, 0, 0);
                __builtin_amdgcn_s_setprio(0);
            }
        }
    }

    // l complete per q-column in every lfrag register (rows identical)
    const float ls = lfrag[0];

    // normalize partial (|o/l| <= max|V| -- f16-safe), store f16 RNE + l,m f32
    const float invl = 1.0f / ls;
    const int qg = q0 + lq;
    const size_t prow = ((size_t)(hf * 16 + bh) * NTOK + qg);
    {
        unsigned w0 = pk_f16_rne(o0[0] * invl, o0[1] * invl);
        unsigned w1 = pk_f16_rne(o0[2] * invl, o0[3] * invl);
        *(uint2*)&P_O[prow * 32 + 4 * g] = make_uint2(w0, w1);
        unsigned w2 = pk_f16_rne(o1[0] * invl, o1[1] * invl);
        unsigned w3 = pk_f16_rne(o1[2] * invl, o1[3] * invl);
        *(uint2*)&P_O[prow * 32 + 16 + 4 * g] = make_uint2(w2, w3);
    }
    if (g == 0) {
        P_l[prow] = ls;
        P_m[prow] = m_;
    }
}

// ---------------- merge: reconcile maxima, weighted average -> AO bf16 hi/lo ----------------
__global__ __launch_bounds__(256) void merge_norm(
    const ushort_t* __restrict__ P_O, const float* __restrict__ P_l,
    const float* __restrict__ P_m,
    ushort_t* __restrict__ AOhi, ushort_t* __restrict__ AOlo)
{
    const int t = blockIdx.x * 256 + threadIdx.x;     // 262144 threads
    const int bhq = t >> 2;                           // bh*4096 + q
    const int dq = (t & 3) << 3;
    union { uint4 q; _Float16 h[8]; } a, b;
    a.q = *(const uint4*)&P_O[(size_t)bhq * 32 + dq];
    b.q = *(const uint4*)&P_O[(size_t)(65536 + bhq) * 32 + dq];
    const float l0 = P_l[bhq], l1 = P_l[65536 + bhq];
    const float m0 = P_m[bhq], m1 = P_m[65536 + bhq];
    const float mstar = fmaxf(m0, m1);
    const float w0r = exp2_fast(m0 - mstar) * l0;
    const float w1r = exp2_fast(m1 - mstar) * l1;
    const float inv = 1.0f / (w0r + w1r);
    const float w0 = w0r * inv, w1 = w1r * inv;
    const int bh = bhq >> 12, q = bhq & 4095;
    const size_t ob = ((size_t)(bh >> 3) * NTOK + q) * CDIM + (bh & 7) * 32 + dq;

    float f[8];
    #pragma unroll
    for (int i = 0; i < 8; ++i) f[i] = (float)a.h[i] * w0 + (float)b.h[i] * w1;

    unsigned h01 = cvt_pk_bf16(f[0], f[1]), h23 = cvt_pk_bf16(f[2], f[3]);
    unsigned h45 = cvt_pk_bf16(f[4], f[5]), h67 = cvt_pk_bf16(f[6], f[7]);
    union { unsigned u; float ff; } x, y;
    x.u = h01 << 16; y.u = h01 & 0xFFFF0000u;
    unsigned l01 = cvt_pk_bf16(f[0] - x.ff, f[1] - y.ff);
    x.u = h23 << 16; y.u = h23 & 0xFFFF0000u;
    unsigned l23 = cvt_pk_bf16(f[2] - x.ff, f[3] - y.ff);
    x.u = h45 << 16; y.u = h45 & 0xFFFF0000u;
    unsigned l45 = cvt_pk_bf16(f[4] - x.ff, f[5] - y.ff);
    x.u = h67 << 16; y.u = h67 & 0xFFFF0000u;
    unsigned l67 = cvt_pk_bf16(f[6] - x.ff, f[7] - y.ff);

    *(uint4*)&AOhi[ob] = make_uint4(h01, h23, h45, h67);
    *(uint4*)&AOlo[ob] = make_uint4(l01, l23, l45, l67);
}

// ---------------- Output projection: split-bf16 MFMA GEMM (proven r10) ----------------
__global__ __launch_bounds__(256) void proj_mfma(
    const ushort_t* __restrict__ AOhi, const ushort_t* __restrict__ AOlo,
    const ushort_t* __restrict__ Wthi, const ushort_t* __restrict__ Wtlo,  // [256][256]
    const float* __restrict__ bias, float* __restrict__ out)
{
    __shared__ __align__(16) ushort_t Ah[64][40], Al[64][40], Bh[64][40], Bl[64][40];

    const int tid = threadIdx.x;
    const int w = tid >> 6, lane = tid & 63, lq = lane & 15, g = lane >> 4;
    const int wm = w >> 1, wn = w & 1;
    const int row0 = blockIdx.x * 64, col0 = blockIdx.y * 64;
    const int sr = tid >> 2, sc = (tid & 3) << 3;

    f32x4 acc[2][2] = {};

    for (int k0 = 0; k0 < CDIM; k0 += 32) {
        __syncthreads();
        *(uint4*)&Ah[sr][sc] = *(const uint4*)&AOhi[(size_t)(row0 + sr) * CDIM + k0 + sc];
        *(uint4*)&Al[sr][sc] = *(const uint4*)&AOlo[(size_t)(row0 + sr) * CDIM + k0 + sc];
        *(uint4*)&Bh[sr][sc] = *(const uint4*)&Wthi[(size_t)(col0 + sr) * CDIM + k0 + sc];
        *(uint4*)&Bl[sr][sc] = *(const uint4*)&Wtlo[(size_t)(col0 + sr) * CDIM + k0 + sc];
        __syncthreads();

        bf16x8 ah[2], al[2], bh[2], bl[2];
        #pragma unroll
        for (int i = 0; i < 2; ++i) {
            ah[i] = *(const bf16x8*)&Ah[wm * 32 + i * 16 + lq][g * 8];
            al[i] = *(const bf16x8*)&Al[wm * 32 + i * 16 + lq][g * 8];
        }
        #pragma unroll
        for (int j = 0; j < 2; ++j) {
            bh[j] = *(const bf16x8*)&Bh[wn * 32 + j * 16 + lq][g * 8];
            bl[j] = *(const bf16x8*)&Bl[wn * 32 + j * 16 + lq][g * 8];
        }
        #pragma unroll
        for (int i = 0; i < 2; ++i)
            #pragma unroll
            for (int j = 0; j < 2; ++j) {
                acc[i][j] = __builtin_amdgcn_mfma_f32_16x16x32_bf16(ah[i], bh[j], acc[i][j], 0, 0, 0);
                acc[i][j] = __builtin_amdgcn_mfma_f32_16x16x32_bf16(ah[i], bl[j], acc[i][j], 0, 0, 0);
                acc[i][j] = __builtin_amdgcn_mfma_f32_16x16x32_bf16(al[i], bh[j], acc[i][j], 0, 0, 0);
            }
    }

    #pragma unroll
    for (int j = 0; j < 2; ++j) {
        const int gcol = col0 + wn * 32 + j * 16 + lq;
        const float bv = bias[gcol];
        #pragma unroll
        for (int i = 0; i < 2; ++i) {
            #pragma unroll
            for (int r = 0; r < 4; ++r) {
                const int grow = row0 + wm * 32 + i * 16 + 4 * g + r;
                out[(size_t)grow * CDIM + gcol] = acc[i][j][r] + bv;
            }
        }
    }
}

extern "C" void kernel_launch(void* const* d_in, const int* in_sizes, int n_in,
                              void* d_out, int out_size, void* d_ws, size_t ws_size,
                              hipStream_t stream)
{
    const float* x      = (const float*)d_in[0];
    const float* w_qkv  = (const float*)d_in[1];
    const float* b_qkv  = (const float*)d_in[2];
    const float* w_proj = (const float*)d_in[3];
    const float* b_proj = (const float*)d_in[4];
    // d_in[5] rel_bias: per-head scalar over the full score matrix -> softmax no-op.

    float* out = (float*)d_out;

    // ws layout (22MB, phase-safe):
    //  [ 0, 4M): Q hi               (qkv->attn)
    //  [ 4, 8M): K hi               (qkv->attn), then AOhi (merge->proj)
    //  [ 8,12M): V hi               (qkv->attn), then AOlo (merge->proj)
    //  [12,13M): weights Wqt/Wpt hi/lo
    //  [13,21M): partials P_O (attn->merge)
    //  [21M+):   P_l (512KB), P_m (512KB)
    char* p = (char*)d_ws;
    ushort_t* Qhi   = (ushort_t*)(p);
    ushort_t* Khi   = (ushort_t*)(p + 4194304);
    ushort_t* Vhi   = (ushort_t*)(p + 8388608);
    ushort_t* Wqthi = (ushort_t*)(p + 12582912);
    ushort_t* Wqtlo = (ushort_t*)(p + 12582912 + 393216);
    ushort_t* Wpthi = (ushort_t*)(p + 12582912 + 786432);
    ushort_t* Wptlo = (ushort_t*)(p + 12582912 + 917504);
    ushort_t* P_O   = (ushort_t*)(p + 13631488);            // 13M, 8MB
    float*    P_l   = (float*)(p + 22020096);               // 512KB
    float*    P_m   = (float*)(p + 22544384);               // 512KB
    ushort_t* AOhi  = Khi;                                  // K dead after attn
    ushort_t* AOlo  = Vhi;                                  // V dead after attn

    // 0) prep: transpose+split weights (X split fused into qkv_mfma)
    prep_wt<<<dim3(24, 8), 256, 0, stream>>>(w_qkv, Wqthi, Wqtlo, 256, 768);
    prep_wt<<<dim3(8, 8), 256, 0, stream>>>(w_proj, Wpthi, Wptlo, 256, 256);

    // 1) QKV projection (MFMA, fused f32->hi/lo staging; Q/K/V hi-only)
    qkv_mfma<<<dim3(MROWS / 64, 768 / 64), 256, 0, stream>>>(
        x, Wqthi, Wqtlo, b_qkv, Qhi, Khi, Vhi);

    // 2) attention halves (2048 blocks, KVBLK=128, 1-term QK, setprio)
    attn_v19<<<2048, 256, 0, stream>>>(Qhi, Khi, Vhi, P_O, P_l, P_m);

    // 3) merge partials (max-reconciled weighted average) -> AO bf16 hi/lo
    merge_norm<<<1024, 256, 0, stream>>>(P_O, P_l, P_m, AOhi, AOlo);

    // 4) output projection (MFMA)
    proj_mfma<<<dim3(MROWS / 64, CDIM / 64), 256, 0, stream>>>(
        AOhi, AOlo, Wpthi, Wptlo, b_proj, out);
}